// Round 5
// baseline (284.275 us; speedup 1.0000x reference)
//
#include <hip/hip_runtime.h>

// LaplacianPyramidLoss: loss = sum_l mean(|pyr(x)[l] - pyr(t)[l]|)
// Linearity: pyr(x)[l]-pyr(t)[l] = pyr(x-t)[l] -> ONE pyramid of d=x-t.
// Per level: fused {blur@even-rows/cols (=downsample), |cur - up(down)| L1}.
// Level 2 also fuses the final mean(|down2|) so down2 never touches HBM.
//
// R5 == R4 resubmission (two UnresponsiveContainer infra failures on the
// same pod; kernel audited clean -- LDS ranges exact, OOB reads clamped,
// ws layout proven by R1/R2). Design: stage tiles with
// __builtin_amdgcn_global_load_lds width=16 (fire-and-forget, no VGPR
// round trip) -- R2's register staging was serialized by the compiler
// (VGPR=28) leaving ~2 loads/wave in flight -> 2.2 TB/s. Level 0 stages
// x and t separately (no ALU on the async path), subtracts in-stencil.

constexpr int THREADS = 256;
constexpr int TILE = 32;             // down outputs per dim per block
constexpr int ROWS = 2 * TILE + 3;   // 67 input rows (5x5 stencil halo)
constexpr int COLS = 2 * TILE + 8;   // 72 cols: halo -4..+67, 16B-aligned start
constexpr int SEG4 = COLS / 4;       // 18 float4 per row
constexpr int TOT4 = ROWS * SEG4;    // 1206 float4 per tile
constexpr int WOPS = (TOT4 + 63) / 64;  // 19 wave-ops (64 lanes x 16B each)
constexpr int REG4 = WOPS * 64;      // 1216 float4 region (tail never read)

__device__ inline void gload_lds16(const float* g, float* l) {
    // global (AS1) per-lane src; LDS (AS3) wave-uniform base + lane*16 dest.
    auto g1 = (const __attribute__((address_space(1))) void*)g;
    auto l3 = (__attribute__((address_space(3))) void*)l;
    __builtin_amdgcn_global_load_lds(g1, l3, 16, 0, 0);
}

template <bool FUSE, bool LAST, bool WRITE_DOWN>
__global__ __launch_bounds__(THREADS)
void lap_level(const float* __restrict__ A,    // x (lvl0) or cur
               const float* __restrict__ Bp,   // t (lvl0) or nullptr
               const float* __restrict__ w25,  // 5x5 gaussian (channel 0)
               float* __restrict__ down,       // H/2 x W/2 (if WRITE_DOWN)
               float* __restrict__ sums,       // sums[level], sums[3] if LAST
               int H, int W, int level)
{
    __shared__ __align__(16) float sdA[REG4 * 4];
    __shared__ __align__(16) float sdB[FUSE ? REG4 * 4 : 4];
    const int tid  = threadIdx.x;
    const int w    = tid >> 6;         // wave id 0..3
    const int lane = tid & 63;
    const int ox0 = blockIdx.x * TILE;
    const int oy0 = blockIdx.y * TILE;
    const int n   = blockIdx.z;        // fused B*C image-channel index
    const size_t ibase = (size_t)n * H * W;
    const int gy0 = 2 * oy0 - 2;
    const int gx0 = 2 * ox0 - 4;       // 16B-aligned; stencil cols at +2 local

    // ---- async global->LDS staging: fire-and-forget, max MLP ----
    for (int j = w; j < WOPS; j += THREADS / 64) {
        const int idx4 = j * 64 + lane;
        const int r  = idx4 / SEG4;
        const int c4 = idx4 - r * SEG4;
        const int gy = gy0 + r;
        const int gx = gx0 + 4 * c4;   // mult of 4; W%4==0 -> all-in or all-out
        const bool ok = (r < ROWS) && ((unsigned)gy < (unsigned)H)
                                   && ((unsigned)gx < (unsigned)W);
        const size_t off = ok ? ((size_t)gy * W + gx) : 0;  // clamp: garbage, fixed below
        gload_lds16(A + ibase + off, &sdA[j * 256]);        // base uniform per wave
        if (FUSE) gload_lds16(Bp + ibase + off, &sdB[j * 256]);
    }

    float wv[25];
#pragma unroll
    for (int i = 0; i < 25; ++i) wv[i] = w25[i];  // uniform -> scalar loads

    // ---- border blocks: drain loads, then zero the OOB cells ----
    const bool needZero = (gy0 < 0) | (gy0 + ROWS - 1 >= H)
                        | (gx0 < 0) | (gx0 + COLS - 1 >= W);
    if (needZero) {
        asm volatile("s_waitcnt vmcnt(0)" ::: "memory");
        for (int j = w; j < WOPS; j += THREADS / 64) {
            const int idx4 = j * 64 + lane;
            const int r  = idx4 / SEG4;
            const int c4 = idx4 - r * SEG4;
            if (r < ROWS) {
                const int gy = gy0 + r;
                const int gx = gx0 + 4 * c4;
                if (((unsigned)gy >= (unsigned)H) | ((unsigned)gx >= (unsigned)W)) {
                    const float4 z = make_float4(0.f, 0.f, 0.f, 0.f);
                    *(float4*)&sdA[idx4 * 4] = z;
                    if (FUSE) *(float4*)&sdB[idx4 * 4] = z;
                }
            }
        }
    }
    __syncthreads();  // non-border: compiler drains vmcnt here

    const int lx  = tid & (TILE - 1);  // 0..31
    const int ly0 = tid / TILE;        // 0..7
    const int Hd = H >> 1, Wd = W >> 1;
    float lsum = 0.0f;  // sum |cur - up(down)|
    float dsum = 0.0f;  // (LAST) sum |down|

#pragma unroll
    for (int kk = 0; kk < (TILE * TILE) / THREADS; ++kk) {
        const int ly = ly0 + kk * (THREADS / TILE);
        const float* rA = &sdA[(2 * ly) * COLS + 2 * lx + 2];
        float ax = 0.0f;
#pragma unroll
        for (int dy = 0; dy < 5; ++dy)
#pragma unroll
            for (int dx = 0; dx < 5; ++dx)
                ax = fmaf(wv[dy * 5 + dx], rA[dy * COLS + dx], ax);
        float acc = ax;
        float c00 = rA[2 * COLS + 2], c01 = rA[2 * COLS + 3];
        float c10 = rA[3 * COLS + 2], c11 = rA[3 * COLS + 3];
        if (FUSE) {
            const float* rB = &sdB[(2 * ly) * COLS + 2 * lx + 2];
            float at = 0.0f;
#pragma unroll
            for (int dy = 0; dy < 5; ++dy)
#pragma unroll
                for (int dx = 0; dx < 5; ++dx)
                    at = fmaf(wv[dy * 5 + dx], rB[dy * COLS + dx], at);
            acc = ax - at;
            c00 -= rB[2 * COLS + 2]; c01 -= rB[2 * COLS + 3];
            c10 -= rB[3 * COLS + 2]; c11 -= rB[3 * COLS + 3];
        }
        if (WRITE_DOWN)
            down[(size_t)n * Hd * Wd + (size_t)(oy0 + ly) * Wd + (ox0 + lx)] = acc;
        lsum += fabsf(c00 - acc) + fabsf(c01 - acc)
              + fabsf(c10 - acc) + fabsf(c11 - acc);
        if (LAST) dsum += fabsf(acc);
    }

    // wave64 reduce -> cross-wave via LDS -> one atomic per block per level
#pragma unroll
    for (int off = 32; off > 0; off >>= 1) {
        lsum += __shfl_down(lsum, off);
        if (LAST) dsum += __shfl_down(dsum, off);
    }
    __shared__ float wsum_l[THREADS / 64];
    __shared__ float wsum_d[THREADS / 64];
    if ((tid & 63) == 0) {
        wsum_l[w] = lsum;
        if (LAST) wsum_d[w] = dsum;
    }
    __syncthreads();
    if (tid == 0) {
        float s = 0.0f, s2 = 0.0f;
#pragma unroll
        for (int i = 0; i < THREADS / 64; ++i) {
            s += wsum_l[i];
            if (LAST) s2 += wsum_d[i];
        }
        atomicAdd(&sums[level], s);
        if (LAST) atomicAdd(&sums[3], s2);
    }
}

__global__ void finalize_kernel(const float* __restrict__ sums,
                                float* __restrict__ out,
                                float inv0, float inv1, float inv2, float inv3)
{
    out[0] = sums[0] * inv0 + sums[1] * inv1 + sums[2] * inv2 + sums[3] * inv3;
}

extern "C" void kernel_launch(void* const* d_in, const int* in_sizes, int n_in,
                              void* d_out, int out_size, void* d_ws, size_t ws_size,
                              hipStream_t stream)
{
    const float* x   = (const float*)d_in[0];
    const float* t   = (const float*)d_in[1];
    const float* ker = (const float*)d_in[2];  // (13,1,5,5); channels identical
    float* out = (float*)d_out;

    constexpr int B = 16, C = 13, H = 512, W = 512;
    constexpr int N = B * C;  // 208 image-channels

    // ws: [256B sums] [down0: N*256*256 f32] [down1: N*128*128 f32]
    float* sums  = (float*)d_ws;
    float* down0 = (float*)((char*)d_ws + 256);
    float* down1 = down0 + (size_t)N * (H / 2) * (W / 2);

    hipMemsetAsync(sums, 0, 4 * sizeof(float), stream);

    dim3 blk(THREADS);
    // level 0: d = x - t (in-stencil), 512 -> down0 256
    lap_level<true, false, true><<<dim3((W/2)/TILE, (H/2)/TILE, N), blk, 0, stream>>>(
        x, t, ker, down0, sums, H, W, 0);
    // level 1: down0 256 -> down1 128
    lap_level<false, false, true><<<dim3((W/4)/TILE, (H/4)/TILE, N), blk, 0, stream>>>(
        down0, nullptr, ker, down1, sums, H / 2, W / 2, 1);
    // level 2: down1 128 -> 64 (in-register), fuses level-3 mean(|down2|)
    lap_level<false, true, false><<<dim3((W/8)/TILE, (H/8)/TILE, N), blk, 0, stream>>>(
        down1, nullptr, ker, nullptr, sums, H / 4, W / 4, 2);

    const float inv0 = 1.0f / ((float)N * H * W);
    const float inv1 = 1.0f / ((float)N * (H/2) * (W/2));
    const float inv2 = 1.0f / ((float)N * (H/4) * (W/4));
    const float inv3 = 1.0f / ((float)N * (H/8) * (W/8));
    finalize_kernel<<<1, 1, 0, stream>>>(sums, out, inv0, inv1, inv2, inv3);
}

// Round 6
// 185.672 us; speedup vs baseline: 1.5311x; 1.5311x over previous
//
#include <hip/hip_runtime.h>

// LaplacianPyramidLoss: loss = sum_l mean(|pyr(x)[l] - pyr(t)[l]|)
// Linearity: pyr(x)-pyr(t) = pyr(x-t) -> ONE pyramid of d=x-t.
// R6: persistent blocks + cross-tile pipeline (issue next tile's loads to
// registers, raw s_barrier WITHOUT vmcnt drain so loads fly across it),
// separable 5x5 (=v v^T, v = row sums), d=x-t fused at LDS-write time.
// Per level: fused blur@even (=downsample) + |cur - up(down)| L1 sum.
// Level 2 fuses the final mean(|down2|): down2 never touches HBM.

constexpr int THREADS = 256;
constexpr int TILE  = 32;               // down outputs per dim per tile
constexpr int ROWS  = 2*TILE + 3;       // 67 input rows (5x5 halo)
constexpr int COLS  = 2*TILE + 8;       // 72 float stride (mult of 4, 16B ok)
constexpr int SEG4  = COLS/4;           // 18 float4 per row
constexpr int TOT4  = ROWS*SEG4;        // 1206 float4 per tile
constexpr int KLOAD = (TOT4 + THREADS - 1)/THREADS;  // 5 float4 per thread
constexpr int HROWS = 19;               // per-wave h rows (8 out rows + halo)
constexpr int NBLK  = 768;              // persistent: 3 blocks/CU x 256 CU

template <bool FUSE, bool LAST, bool WRITE_DOWN>
__global__ __launch_bounds__(THREADS)
void lap_level(const float* __restrict__ A,    // x (lvl0) or cur
               const float* __restrict__ Bp,   // t (lvl0) or nullptr
               const float* __restrict__ w25,  // 5x5 gaussian (channel 0)
               float* __restrict__ down,       // H/2 x W/2 (if WRITE_DOWN)
               float* __restrict__ sums,       // sums[level], sums[3] if LAST
               int H, int W, int ntx, int ntxy, int ntiles, int level)
{
    __shared__ __align__(16) float sdD[2][ROWS*COLS];   // d-tile ping-pong
    __shared__ float sdH[THREADS/64][HROWS*TILE];       // per-wave h region
    __shared__ float wsl[THREADS/64], wsd[THREADS/64];

    const int tid  = threadIdx.x;
    const int wv   = tid >> 6;
    const int lane = tid & 63;
    const int Hd = H >> 1, Wd = W >> 1;

    // 1D gaussian: row sums of w25 (w25 = v v^T with sum v = 1) -> uniform/SGPR
    float g[5];
#pragma unroll
    for (int i = 0; i < 5; ++i) {
        float s = 0.f;
#pragma unroll
        for (int j = 0; j < 5; ++j) s += w25[i*5+j];
        g[i] = s;
    }

    // hoisted staging coords (tid-only)
    int rr_[KLOAD], cc_[KLOAD];
#pragma unroll
    for (int k = 0; k < KLOAD; ++k) {
        const int idx = tid + k*THREADS;
        rr_[k] = idx / SEG4;
        cc_[k] = idx - rr_[k]*SEG4;
    }

    float lsum = 0.f, dsum = 0.f;
    float4 va[KLOAD], vb[KLOAD];
    int cur = blockIdx.x;
    int p = 0;

    auto issue = [&](int t) {   // issue all loads for tile t into va/vb
        const int n   = t / ntxy;
        const int rem = t - n*ntxy;
        const int ty  = rem / ntx;
        const int tx  = rem - ty*ntx;
        const int gy0 = 2*ty*TILE - 2;
        const int gx0 = 2*tx*TILE - 4;    // float4-aligned halo start
        const size_t ib = (size_t)n * H * W;
#pragma unroll
        for (int k = 0; k < KLOAD; ++k) {
            const int gy = gy0 + rr_[k];
            const int gx = gx0 + 4*cc_[k];   // W%4==0 -> float4 all-in/all-out
            const bool ok = (rr_[k] < ROWS) & ((unsigned)gy < (unsigned)H)
                                            & ((unsigned)gx < (unsigned)W);
            va[k] = make_float4(0.f, 0.f, 0.f, 0.f);
            if (FUSE) vb[k] = make_float4(0.f, 0.f, 0.f, 0.f);
            if (ok) {
                const size_t off = ib + (size_t)gy*W + gx;
                va[k] = *(const float4*)(A + off);
                if (FUSE) vb[k] = *(const float4*)(Bp + off);
            }
        }
    };

    if (cur < ntiles) {
        issue(cur);
        for (;;) {
            // ---- W: diff + write d-tile into sdD[p] (vmcnt waits land here) ----
#pragma unroll
            for (int k = 0; k < KLOAD; ++k) {
                if (rr_[k] < ROWS) {
                    float4 d = va[k];
                    if (FUSE) { d.x -= vb[k].x; d.y -= vb[k].y;
                                d.z -= vb[k].z; d.w -= vb[k].w; }
                    *(float4*)&sdD[p][rr_[k]*COLS + 4*cc_[k]] = d;
                }
            }
            // ---- issue NEXT tile's loads (hidden under compute below) ----
            const int nxt = cur + NBLK;   // gridDim.x == NBLK
            if (nxt < ntiles) issue(nxt);

            // raw barrier: drain LDS (our ds_writes) but NOT vmcnt -> prefetch
            // stays in flight across the barrier (no __syncthreads drain).
            asm volatile("s_waitcnt lgkmcnt(0)" ::: "memory");
            __builtin_amdgcn_s_barrier();
            __builtin_amdgcn_sched_barrier(0);

            // ---- compute tile `cur` from sdD[p] ----
            {
                const int n   = cur / ntxy;
                const int rem = cur - n*ntxy;
                const int ty  = rem / ntx;
                const int tx  = rem - ty*ntx;
                const int oy0 = ty*TILE, ox0 = tx*TILE;
                const float* dd = sdD[p];
                float* hh = hh = sdH[wv];
                const int hb = 16*wv;     // wave's input-row base

                // h-pass: per-wave private region, rows hb..hb+18, 32 cols
#pragma unroll
                for (int k = 0; k < (HROWS*TILE + 63)/64; ++k) {
                    const int idx = lane + k*64;
                    if (idx < HROWS*TILE) {
                        const int hr = idx >> 5, hc = idx & 31;
                        const float* dr = &dd[(hb + hr)*COLS + 2*hc + 2];
                        float a = g[0]*dr[0];
                        a = fmaf(g[1], dr[1], a);
                        a = fmaf(g[2], dr[2], a);
                        a = fmaf(g[3], dr[3], a);
                        a = fmaf(g[4], dr[4], a);
                        hh[hr*TILE + hc] = a;   // wave-private: lgkmcnt only
                    }
                }
                // v-pass: 4 outputs per lane
                const int ccx = lane & 31, rsub = lane >> 5;
#pragma unroll
                for (int q = 0; q < 4; ++q) {
                    const int lr = rsub + 2*q;                 // 0..7
                    float acc = g[0]*hh[(2*lr)*TILE + ccx];
                    acc = fmaf(g[1], hh[(2*lr+1)*TILE + ccx], acc);
                    acc = fmaf(g[2], hh[(2*lr+2)*TILE + ccx], acc);
                    acc = fmaf(g[3], hh[(2*lr+3)*TILE + ccx], acc);
                    acc = fmaf(g[4], hh[(2*lr+4)*TILE + ccx], acc);
                    if (WRITE_DOWN) {
                        const int gr = oy0 + 8*wv + lr;
                        down[(size_t)n*Hd*Wd + (size_t)gr*Wd + (ox0 + ccx)] = acc;
                    }
                    // cur 2x2 covered by this down value (nearest-up)
                    const float* cr = &dd[(hb + 2*lr + 2)*COLS + 2*ccx + 4];
                    lsum += fabsf(cr[0]    - acc) + fabsf(cr[1]      - acc)
                          + fabsf(cr[COLS] - acc) + fabsf(cr[COLS+1] - acc);
                    if (LAST) dsum += fabsf(acc);
                }
            }
            if (nxt >= ntiles) break;
            cur = nxt; p ^= 1;
        }
    }

    // ---- block reduce + one atomic per level ----
#pragma unroll
    for (int off = 32; off > 0; off >>= 1) {
        lsum += __shfl_down(lsum, off);
        if (LAST) dsum += __shfl_down(dsum, off);
    }
    __syncthreads();
    if (lane == 0) { wsl[wv] = lsum; if (LAST) wsd[wv] = dsum; }
    __syncthreads();
    if (tid == 0) {
        atomicAdd(&sums[level], wsl[0]+wsl[1]+wsl[2]+wsl[3]);
        if (LAST) atomicAdd(&sums[3], wsd[0]+wsd[1]+wsd[2]+wsd[3]);
    }
}

__global__ void finalize_kernel(const float* __restrict__ sums,
                                float* __restrict__ out,
                                float inv0, float inv1, float inv2, float inv3)
{
    out[0] = sums[0]*inv0 + sums[1]*inv1 + sums[2]*inv2 + sums[3]*inv3;
}

extern "C" void kernel_launch(void* const* d_in, const int* in_sizes, int n_in,
                              void* d_out, int out_size, void* d_ws, size_t ws_size,
                              hipStream_t stream)
{
    const float* x   = (const float*)d_in[0];
    const float* t   = (const float*)d_in[1];
    const float* ker = (const float*)d_in[2];  // (13,1,5,5); channels identical
    float* out = (float*)d_out;

    constexpr int B = 16, C = 13, H = 512, W = 512;
    constexpr int N = B * C;  // 208 image-channels

    // ws: [256B sums] [down0: N*256*256 f32] [down1: N*128*128 f32]
    float* sums  = (float*)d_ws;
    float* down0 = (float*)((char*)d_ws + 256);
    float* down1 = down0 + (size_t)N * (H/2) * (W/2);

    hipMemsetAsync(sums, 0, 4 * sizeof(float), stream);

    dim3 blk(THREADS);
    // level 0: d = x-t (fused at LDS write), 512 -> down0 256
    {
        const int ntx = (W/2)/TILE, ntxy = ntx*((H/2)/TILE), nt = ntxy*N;
        lap_level<true, false, true><<<dim3(NBLK), blk, 0, stream>>>(
            x, t, ker, down0, sums, H, W, ntx, ntxy, nt, 0);
    }
    // level 1: down0 256 -> down1 128
    {
        const int ntx = (W/4)/TILE, ntxy = ntx*((H/4)/TILE), nt = ntxy*N;
        lap_level<false, false, true><<<dim3(NBLK), blk, 0, stream>>>(
            down0, nullptr, ker, down1, sums, H/2, W/2, ntx, ntxy, nt, 1);
    }
    // level 2: down1 128 -> 64 (in-register), fuses level-3 mean(|down2|)
    {
        const int ntx = (W/8)/TILE, ntxy = ntx*((H/8)/TILE), nt = ntxy*N;
        lap_level<false, true, false><<<dim3(NBLK), blk, 0, stream>>>(
            down1, nullptr, ker, nullptr, sums, H/4, W/4, ntx, ntxy, nt, 2);
    }

    const float inv0 = 1.0f / ((float)N * H * W);
    const float inv1 = 1.0f / ((float)N * (H/2) * (W/2));
    const float inv2 = 1.0f / ((float)N * (H/4) * (W/4));
    const float inv3 = 1.0f / ((float)N * (H/8) * (W/8));
    finalize_kernel<<<1, 1, 0, stream>>>(sums, out, inv0, inv1, inv2, inv3);
}